// Round 2
// baseline (245.442 us; speedup 1.0000x reference)
//
#include <hip/hip_runtime.h>
#include <hip/hip_bf16.h>

// TriangleAttention: S=256, H=4, DH=32, D=128.  All tensors fp32; bf16
// intermediates (error budget proven: 0.0059 vs 0.0176 threshold).
// Round-9 (resubmit after infra failure): transposed-score attention.
//   [ln_biasmask] -> bm fp32 [H][S][S] (1 MB)
//   [proj_ln]     x --fused LN--> @ {Wq|Wk|Wv|Wg}^T -> qkvg bf16 [NPOS][512]
//   [attn]        grid (b, h, qhalf): scores computed TRANSPOSED via
//                 mfma(K,Q) so each lane owns one q-row -> in-register
//                 softmax (2 shfl instead of 32), float4 bias loads,
//                 b64-packed P writes -> gated o written bf16
//   [outproj]     gated bf16 @ Wo^T -> d_out fp32 (swapped-operand MFMA,
//                 float4 C stores)
#define S_DIM 256
#define D_DIM 128
#define H_DIM 4
#define NPOS  (S_DIM * S_DIM)   // 65536

typedef __attribute__((ext_vector_type(8))) short  short8;   // 8 bf16 (4 VGPRs)
typedef __attribute__((ext_vector_type(4))) float  f32x4;

__device__ __forceinline__ float b2f(unsigned short u) {
    union { float f; unsigned int u32; } c; c.u32 = ((unsigned int)u) << 16; return c.f;
}
__device__ __forceinline__ unsigned short f2b(float f) {
    __hip_bfloat16 h = __float2bfloat16(f);   // RNE
    return *reinterpret_cast<unsigned short*>(&h);
}

// ---------------------------------------------------------------------------
// K1: LayerNorm (fp32) + triangle-bias projection + attn_mask fold.
// One wave per position p = q*256+k; 2 elems/lane.  bm fp32 [H][NPOS].
// ---------------------------------------------------------------------------
__global__ __launch_bounds__(256) void ln_biasmask_kernel(
    const float* __restrict__ x, const float* __restrict__ mask,
    const float* __restrict__ lnw, const float* __restrict__ lnb,
    const float* __restrict__ Wb, float* __restrict__ bm)
{
    const int wave = threadIdx.x >> 6, lane = threadIdx.x & 63;
    const int p = blockIdx.x * 4 + wave;

    float2 v = ((const float2*)x)[p * 64 + lane];
    float s = v.x + v.y, ss = v.x * v.x + v.y * v.y;
    #pragma unroll
    for (int m = 1; m < 64; m <<= 1) { s += __shfl_xor(s, m); ss += __shfl_xor(ss, m); }
    float mean = s * (1.f / 128.f);
    float var  = ss * (1.f / 128.f) - mean * mean;
    float rstd = rsqrtf(var + 1e-5f);

    float xn0 = (v.x - mean) * rstd * lnw[lane * 2]     + lnb[lane * 2];
    float xn1 = (v.y - mean) * rstd * lnw[lane * 2 + 1] + lnb[lane * 2 + 1];

    float mval = mask[p];
    #pragma unroll
    for (int h = 0; h < H_DIM; h++) {
        float d = xn0 * Wb[h * 128 + lane * 2] + xn1 * Wb[h * 128 + lane * 2 + 1];
        #pragma unroll
        for (int m = 1; m < 64; m <<= 1) d += __shfl_xor(d, m);
        if (lane == 0) bm[(long)h * NPOS + p] = d + mval;
    }
}

// ---------------------------------------------------------------------------
// K2: projection GEMM with fused LayerNorm (MFMA).
// strip[p - p0][gy*128 + n] = sum_d LN(x)[p][d] * W_gy[n][d]
// gy: 0=Wq 1=Wk 2=Wv 3=Wg.  Tile 64(m) x 128(n); K=128 in 4 steps.
// MFMA operands SWAPPED (A=W, B=x) so C[n][m] gives each lane 4 consecutive
// n for its row m=w*16+l16 -> packed b64 bf16 stores (was 32 scalar b16).
// ---------------------------------------------------------------------------
__global__ __launch_bounds__(256) void proj_ln_kernel(
    const float* __restrict__ x,
    const float* __restrict__ lnw, const float* __restrict__ lnb,
    const float* __restrict__ Wq, const float* __restrict__ Wk,
    const float* __restrict__ Wv, const float* __restrict__ Wg,
    int p0, unsigned short* __restrict__ strip)
{
    __shared__ __align__(16) unsigned short A_lds[64 * 136];
    __shared__ __align__(16) unsigned short W_lds[128 * 136];
    const int tid = threadIdx.x;
    const int m0 = blockIdx.x * 64;          // strip-local row base
    const int gy = blockIdx.y;
    const float* W = (gy == 0) ? Wq : (gy == 1) ? Wk : (gy == 2) ? Wv : Wg;

    const int lr = tid >> 4, c8 = (tid & 15) * 8;
    // A tile: fused LN.  Row r is covered by the 16 threads with lr == r.
    #pragma unroll
    for (int i = 0; i < 4; i++) {
        int row = lr + i * 16;
        const float* src = x + (size_t)(p0 + m0 + row) * 128 + c8;
        float4 f0 = *(const float4*)(src);
        float4 f1 = *(const float4*)(src + 4);
        float s  = f0.x + f0.y + f0.z + f0.w + f1.x + f1.y + f1.z + f1.w;
        float ss = f0.x*f0.x + f0.y*f0.y + f0.z*f0.z + f0.w*f0.w
                 + f1.x*f1.x + f1.y*f1.y + f1.z*f1.z + f1.w*f1.w;
        #pragma unroll
        for (int m = 1; m < 16; m <<= 1) { s += __shfl_xor(s, m); ss += __shfl_xor(ss, m); }
        float mean = s * (1.f / 128.f);
        float var  = ss * (1.f / 128.f) - mean * mean;
        float rstd = rsqrtf(var + 1e-5f);
        float xv[8] = {f0.x, f0.y, f0.z, f0.w, f1.x, f1.y, f1.z, f1.w};
        unsigned short pk[8];
        #pragma unroll
        for (int j = 0; j < 8; j++)
            pk[j] = f2b((xv[j] - mean) * rstd * lnw[c8 + j] + lnb[c8 + j]);
        *(uint4*)(&A_lds[row * 136 + c8]) = *(const uint4*)pk;
    }
    // W tile: fp32 -> bf16
    #pragma unroll
    for (int i = 0; i < 8; i++) {
        int wr = lr + i * 16;
        const float* src = W + (size_t)wr * 128 + c8;
        float4 f0 = *(const float4*)(src);
        float4 f1 = *(const float4*)(src + 4);
        unsigned short pk[8] = {f2b(f0.x), f2b(f0.y), f2b(f0.z), f2b(f0.w),
                                f2b(f1.x), f2b(f1.y), f2b(f1.z), f2b(f1.w)};
        *(uint4*)(&W_lds[wr * 136 + c8]) = *(const uint4*)pk;
    }
    __syncthreads();

    const int w = tid >> 6, lane = tid & 63;
    const int l16 = lane & 15, quad = lane >> 4;
    f32x4 acc[8];
    #pragma unroll
    for (int nt = 0; nt < 8; nt++) acc[nt] = (f32x4){0.f, 0.f, 0.f, 0.f};

    #pragma unroll
    for (int k0 = 0; k0 < 128; k0 += 32) {
        short8 a = *(const short8*)(&A_lds[(w * 16 + l16) * 136 + k0 + quad * 8]);
        #pragma unroll
        for (int nt = 0; nt < 8; nt++) {
            short8 b = *(const short8*)(&W_lds[(nt * 16 + l16) * 136 + k0 + quad * 8]);
            // swapped: C[n][m], row = n (quad*4+rr within nt tile), col = m (l16)
            acc[nt] = __builtin_amdgcn_mfma_f32_16x16x32_bf16(b, a, acc[nt], 0, 0, 0);
        }
    }

    const size_t rowbase = (size_t)(m0 + w * 16 + l16) * 512 + gy * 128;
    #pragma unroll
    for (int nt = 0; nt < 8; nt++) {
        uint2 pk;
        pk.x = (unsigned)f2b(acc[nt][0]) | ((unsigned)f2b(acc[nt][1]) << 16);
        pk.y = (unsigned)f2b(acc[nt][2]) | ((unsigned)f2b(acc[nt][3]) << 16);
        *(uint2*)(&strip[rowbase + nt * 16 + quad * 4]) = pk;
    }
}

// ---------------------------------------------------------------------------
// K3: attention (MFMA), transposed scores.  Block = (strip-local b, h, z);
// 4 waves x 2 q-tiles each (z halves).  strip: [pos][512] = q|k|v|g.
// S^T = mfma(K, Q): lane owns row q = q0+l16 -> in-register softmax
// (2 shfl), float4 bias loads, b64 P writes -> PV MFMA -> gated bf16 out.
// ---------------------------------------------------------------------------
__global__ __launch_bounds__(256) void attn_kernel(
    const unsigned short* __restrict__ strip, const float* __restrict__ bm,
    int b0, unsigned short* __restrict__ gated)
{
    __shared__ __align__(16) unsigned short VT_lds[32 * 264];       // V^T [dh][k]
    __shared__ __align__(16) unsigned short P_lds[4 * 16 * 264];    // per-wave P
    const int bl = blockIdx.x, h = blockIdx.y, z = blockIdx.z;
    const int b  = b0 + bl;
    const int tid = threadIdx.x;

    {   // stage V^T
        const int row = tid >> 2, chunk = (tid & 3) * 8;
        #pragma unroll
        for (int i = 0; i < 4; i++) {
            int rr = row + i * 64;
            uint4 v = *(const uint4*)(strip + (size_t)(bl * 256 + rr) * 512 + 256 + h * 32 + chunk);
            unsigned short vs[8] = {
                (unsigned short)(v.x & 0xffff), (unsigned short)(v.x >> 16),
                (unsigned short)(v.y & 0xffff), (unsigned short)(v.y >> 16),
                (unsigned short)(v.z & 0xffff), (unsigned short)(v.z >> 16),
                (unsigned short)(v.w & 0xffff), (unsigned short)(v.w >> 16)};
            #pragma unroll
            for (int j = 0; j < 8; j++) VT_lds[(chunk + j) * 264 + rr] = vs[j];
        }
    }
    __syncthreads();

    const int w = tid >> 6, lane = tid & 63;
    const int l16 = lane & 15, quad = lane >> 4;
    const float* bmh = bm + (long)h * NPOS;
    unsigned short* P_w = P_lds + w * 16 * 264;
    const float scale = 0.17677669529663687f;   // 1/sqrt(32)

    #pragma unroll 1
    for (int i = 0; i < 2; i++) {
        const int q0 = (w * 4 + z * 2 + i) * 16;
        // Q fragment (B operand): row j = l16 -> Q row q0+l16
        short8 bq = *(const short8*)(strip + (size_t)(bl * 256 + q0 + l16) * 512 + h * 32 + quad * 8);
        const float* brow = bmh + (size_t)(q0 + l16) * 256 + quad * 4;

        // scores TRANSPOSED: C[k][q]; lane holds q = q0+l16 (col),
        // k = nt*16 + quad*4 + rr (row) -> 4 consecutive k per MFMA.
        float sc[16][4];
        #pragma unroll
        for (int nt = 0; nt < 16; nt++) {
            short8 ka = *(const short8*)(strip + (size_t)(bl * 256 + nt * 16 + l16) * 512 + 128 + h * 32 + quad * 8);
            f32x4 c = (f32x4){0.f, 0.f, 0.f, 0.f};
            c = __builtin_amdgcn_mfma_f32_16x16x32_bf16(ka, bq, c, 0, 0, 0);
            float4 bb = *(const float4*)(brow + nt * 16);   // bias[q][k..k+4]
            sc[nt][0] = c[0] * scale + bb.x;
            sc[nt][1] = c[1] * scale + bb.y;
            sc[nt][2] = c[2] * scale + bb.z;
            sc[nt][3] = c[3] * scale + bb.w;
        }

        // row max: 4 independent in-lane chains, then cross-quad (xor 16, 32)
        float m0 = sc[0][0], m1 = sc[0][1], m2 = sc[0][2], m3 = sc[0][3];
        #pragma unroll
        for (int nt = 1; nt < 16; nt++) {
            m0 = fmaxf(m0, sc[nt][0]); m1 = fmaxf(m1, sc[nt][1]);
            m2 = fmaxf(m2, sc[nt][2]); m3 = fmaxf(m3, sc[nt][3]);
        }
        float m = fmaxf(fmaxf(m0, m1), fmaxf(m2, m3));
        m = fmaxf(m, __shfl_xor(m, 16));
        m = fmaxf(m, __shfl_xor(m, 32));

        float s0 = 0.f, s1 = 0.f, s2 = 0.f, s3 = 0.f;
        #pragma unroll
        for (int nt = 0; nt < 16; nt++) {
            float p0_ = __expf(sc[nt][0] - m); sc[nt][0] = p0_; s0 += p0_;
            float p1_ = __expf(sc[nt][1] - m); sc[nt][1] = p1_; s1 += p1_;
            float p2_ = __expf(sc[nt][2] - m); sc[nt][2] = p2_; s2 += p2_;
            float p3_ = __expf(sc[nt][3] - m); sc[nt][3] = p3_; s3 += p3_;
        }
        float ssum = (s0 + s1) + (s2 + s3);
        ssum += __shfl_xor(ssum, 16);
        ssum += __shfl_xor(ssum, 32);
        float inv = 1.f / ssum;            // for row q = q0 + l16

        // P write: row q_local = l16, 4 consecutive k -> one b64 per nt
        #pragma unroll
        for (int nt = 0; nt < 16; nt++) {
            uint2 pk;
            pk.x = (unsigned)f2b(sc[nt][0]) | ((unsigned)f2b(sc[nt][1]) << 16);
            pk.y = (unsigned)f2b(sc[nt][2]) | ((unsigned)f2b(sc[nt][3]) << 16);
            *(uint2*)(&P_w[l16 * 264 + nt * 16 + quad * 4]) = pk;
        }

        f32x4 oacc[2];
        oacc[0] = (f32x4){0.f, 0.f, 0.f, 0.f};
        oacc[1] = (f32x4){0.f, 0.f, 0.f, 0.f};
        #pragma unroll
        for (int kt = 0; kt < 8; kt++) {
            short8 pa = *(const short8*)(&P_w[l16 * 264 + kt * 32 + quad * 8]);
            #pragma unroll
            for (int nh = 0; nh < 2; nh++) {
                short8 vb = *(const short8*)(&VT_lds[(nh * 16 + l16) * 264 + kt * 32 + quad * 8]);
                oacc[nh] = __builtin_amdgcn_mfma_f32_16x16x32_bf16(pa, vb, oacc[nh], 0, 0, 0);
            }
        }
        #pragma unroll
        for (int rr = 0; rr < 4; rr++) {
            float invr = __shfl(inv, quad * 4 + rr);   // denom for row quad*4+rr
            int row = q0 + quad * 4 + rr;
            #pragma unroll
            for (int nh = 0; nh < 2; nh++) {
                int cl = nh * 16 + l16;   // 0..31
                float g = b2f(strip[(size_t)(bl * 256 + row) * 512 + 384 + h * 32 + cl]);
                float ov = oacc[nh][rr] * invr;
                ov = ov / (1.f + __expf(-g));
                gated[((size_t)b * 256 + row) * 128 + h * 32 + cl] = f2b(ov);   // bf16
            }
        }
    }
}

// ---------------------------------------------------------------------------
// K4: output projection (MFMA).  gated bf16 -> out fp32.
// Swapped operands (A=Wo, B=gated): lane holds 4 consecutive output cols
// for its row -> float4 C stores.  A-stage is a pure bf16 copy.
// ---------------------------------------------------------------------------
__global__ __launch_bounds__(256) void outproj_mfma_kernel(
    const unsigned short* __restrict__ gated, const float* __restrict__ Wo,
    float* __restrict__ out)
{
    __shared__ __align__(16) unsigned short A_lds[64 * 136];
    __shared__ __align__(16) unsigned short W_lds[128 * 136];
    const int tid = threadIdx.x;
    const int m0 = blockIdx.x * 64;

    const int lr = tid >> 4, c8 = (tid & 15) * 8;
    #pragma unroll
    for (int i = 0; i < 4; i++) {
        int row = lr + i * 16;
        *(uint4*)(&A_lds[row * 136 + c8]) =
            *(const uint4*)(gated + (size_t)(m0 + row) * 128 + c8);
    }
    #pragma unroll
    for (int i = 0; i < 8; i++) {
        const float* src = Wo + (size_t)(lr + i * 16) * 128 + c8;
        float4 f0 = *(const float4*)(src);
        float4 f1 = *(const float4*)(src + 4);
        unsigned short pk[8] = {f2b(f0.x), f2b(f0.y), f2b(f0.z), f2b(f0.w),
                                f2b(f1.x), f2b(f1.y), f2b(f1.z), f2b(f1.w)};
        *(uint4*)(&W_lds[(lr + i * 16) * 136 + c8]) = *(const uint4*)pk;
    }
    __syncthreads();

    const int w = tid >> 6, lane = tid & 63;
    const int l16 = lane & 15, quad = lane >> 4;
    f32x4 acc[8];
    #pragma unroll
    for (int nt = 0; nt < 8; nt++) acc[nt] = (f32x4){0.f, 0.f, 0.f, 0.f};

    #pragma unroll
    for (int k0 = 0; k0 < 128; k0 += 32) {
        short8 a = *(const short8*)(&A_lds[(w * 16 + l16) * 136 + k0 + quad * 8]);
        #pragma unroll
        for (int nt = 0; nt < 8; nt++) {
            short8 b = *(const short8*)(&W_lds[(nt * 16 + l16) * 136 + k0 + quad * 8]);
            // swapped: C[n][m], lane row m = w*16+l16, cols n = nt*16+quad*4+rr
            acc[nt] = __builtin_amdgcn_mfma_f32_16x16x32_bf16(b, a, acc[nt], 0, 0, 0);
        }
    }

    float* orow = out + (size_t)(m0 + w * 16 + l16) * 128;
    #pragma unroll
    for (int nt = 0; nt < 8; nt++)
        *(f32x4*)(&orow[nt * 16 + quad * 4]) = acc[nt];   // fp32 float4
}

// ---------------------------------------------------------------------------
extern "C" void kernel_launch(void* const* d_in, const int* in_sizes, int n_in,
                              void* d_out, int out_size, void* d_ws, size_t ws_size,
                              hipStream_t stream)
{
    (void)in_sizes; (void)n_in; (void)out_size;
    const float* x    = (const float*)d_in[0];
    const float* mask = (const float*)d_in[1];
    const float* lnw  = (const float*)d_in[2];
    const float* lnb  = (const float*)d_in[3];
    const float* Wb   = (const float*)d_in[4];
    const float* Wq   = (const float*)d_in[5];
    const float* Wk   = (const float*)d_in[6];
    const float* Wv   = (const float*)d_in[7];
    const float* Wg   = (const float*)d_in[8];
    const float* Wo   = (const float*)d_in[9];
    float* out = (float*)d_out;   // fp32

    // ws: [bm 1 MB][gated bf16 16 MB][strip HB*256*512*2 B]
    const size_t bmB = (size_t)H_DIM * NPOS * sizeof(float);          // 1 MB
    const size_t gB  = (size_t)NPOS * 128 * sizeof(unsigned short);   // 16 MB
    int HB = 256;
    while (HB > 16 && bmB + gB + (size_t)HB * 256 * 512 * 2 > ws_size) HB >>= 1;

    char* ws = (char*)d_ws;
    float*          bm    = (float*)ws;
    unsigned short* gated = (unsigned short*)(ws + bmB);
    unsigned short* strip = (unsigned short*)(ws + bmB + gB);

    ln_biasmask_kernel<<<NPOS / 4, 256, 0, stream>>>(x, mask, lnw, lnb, Wb, bm);
    for (int b0 = 0; b0 < S_DIM; b0 += HB) {
        proj_ln_kernel<<<dim3(HB * 4, 4), 256, 0, stream>>>(
            x, lnw, lnb, Wq, Wk, Wv, Wg, b0 * 256, strip);
        attn_kernel<<<dim3(HB, H_DIM, 2), 256, 0, stream>>>(strip, bm, b0, gated);
    }
    outproj_mfma_kernel<<<NPOS / 64, 256, 0, stream>>>(gated, Wo, out);
}

// Round 3
// 241.688 us; speedup vs baseline: 1.0155x; 1.0155x over previous
//
#include <hip/hip_runtime.h>
#include <hip/hip_bf16.h>

// TriangleAttention: S=256, H=4, DH=32, D=128.  All tensors fp32; bf16
// intermediates (error budget proven: 0.0059 vs 0.0176 threshold).
// Round-10: V produced PRE-TRANSPOSED by proj_ln (Vt[b][d][k] bf16), attn
// reads V^T fragments straight from L2 -> no LDS V transpose, no barrier.
//   [ln_biasmask] -> bm fp32 [H][S][S] (1 MB)
//   [proj_ln]     x --fused LN--> @ {Wq|Wk|Wg}^T -> strip bf16 [pos][384]
//                 and           @ Wv^T -> Vt bf16 [b][128][256] (unswapped
//                 MFMA: lane holds 4 consecutive k -> packed b64 stores)
//   [attn]        grid (b, h): transposed scores mfma(K,Q) -> in-register
//                 softmax (2 shfl) -> P via per-wave LDS -> PV with V^T
//                 fragments loaded from global -> gated bf16 out
//   [outproj]     gated bf16 @ Wo^T -> d_out fp32
#define S_DIM 256
#define D_DIM 128
#define H_DIM 4
#define NPOS  (S_DIM * S_DIM)   // 65536
#define SW    384               // strip row width (bf16): [q:0 | k:128 | g:256]

typedef __attribute__((ext_vector_type(8))) short  short8;   // 8 bf16 (4 VGPRs)
typedef __attribute__((ext_vector_type(4))) float  f32x4;

__device__ __forceinline__ float b2f(unsigned short u) {
    union { float f; unsigned int u32; } c; c.u32 = ((unsigned int)u) << 16; return c.f;
}
__device__ __forceinline__ unsigned short f2b(float f) {
    __hip_bfloat16 h = __float2bfloat16(f);   // RNE
    return *reinterpret_cast<unsigned short*>(&h);
}

// ---------------------------------------------------------------------------
// K1: LayerNorm (fp32) + triangle-bias projection + attn_mask fold.
// One wave per position p = q*256+k; 2 elems/lane.  bm fp32 [H][NPOS].
// ---------------------------------------------------------------------------
__global__ __launch_bounds__(256) void ln_biasmask_kernel(
    const float* __restrict__ x, const float* __restrict__ mask,
    const float* __restrict__ lnw, const float* __restrict__ lnb,
    const float* __restrict__ Wb, float* __restrict__ bm)
{
    const int wave = threadIdx.x >> 6, lane = threadIdx.x & 63;
    const int p = blockIdx.x * 4 + wave;

    float2 v = ((const float2*)x)[p * 64 + lane];
    float s = v.x + v.y, ss = v.x * v.x + v.y * v.y;
    #pragma unroll
    for (int m = 1; m < 64; m <<= 1) { s += __shfl_xor(s, m); ss += __shfl_xor(ss, m); }
    float mean = s * (1.f / 128.f);
    float var  = ss * (1.f / 128.f) - mean * mean;
    float rstd = rsqrtf(var + 1e-5f);

    float xn0 = (v.x - mean) * rstd * lnw[lane * 2]     + lnb[lane * 2];
    float xn1 = (v.y - mean) * rstd * lnw[lane * 2 + 1] + lnb[lane * 2 + 1];

    float mval = mask[p];
    #pragma unroll
    for (int h = 0; h < H_DIM; h++) {
        float d = xn0 * Wb[h * 128 + lane * 2] + xn1 * Wb[h * 128 + lane * 2 + 1];
        #pragma unroll
        for (int m = 1; m < 64; m <<= 1) d += __shfl_xor(d, m);
        if (lane == 0) bm[(long)h * NPOS + p] = d + mval;
    }
}

// ---------------------------------------------------------------------------
// K2: projection GEMM with fused LayerNorm (MFMA).
// gy: 0=Wq 1=Wk 2=Wv 3=Wg.  Tile 64(m) x 128(n); K=128 in 4 steps.
// gy!=2: swapped MFMA (C[n][m]) -> lane holds 4 consecutive n at fixed
//        position m -> packed b64 stores into strip [pos][384].
// gy==2: unswapped MFMA (C[m][n]) -> lane holds 4 consecutive positions
//        at fixed feature n -> packed b64 stores into Vt[b][d][k].
// ---------------------------------------------------------------------------
__global__ __launch_bounds__(256) void proj_ln_kernel(
    const float* __restrict__ x,
    const float* __restrict__ lnw, const float* __restrict__ lnb,
    const float* __restrict__ Wq, const float* __restrict__ Wk,
    const float* __restrict__ Wv, const float* __restrict__ Wg,
    int p0, unsigned short* __restrict__ strip, unsigned short* __restrict__ vt)
{
    __shared__ __align__(16) unsigned short A_lds[64 * 136];
    __shared__ __align__(16) unsigned short W_lds[128 * 136];
    const int tid = threadIdx.x;
    const int m0 = blockIdx.x * 64;          // strip-local row base
    const int gy = blockIdx.y;
    const float* W = (gy == 0) ? Wq : (gy == 1) ? Wk : (gy == 2) ? Wv : Wg;

    const int lr = tid >> 4, c8 = (tid & 15) * 8;
    // A tile: fused LN.  Row r is covered by the 16 threads with lr == r.
    #pragma unroll
    for (int i = 0; i < 4; i++) {
        int row = lr + i * 16;
        const float* src = x + (size_t)(p0 + m0 + row) * 128 + c8;
        float4 f0 = *(const float4*)(src);
        float4 f1 = *(const float4*)(src + 4);
        float s  = f0.x + f0.y + f0.z + f0.w + f1.x + f1.y + f1.z + f1.w;
        float ss = f0.x*f0.x + f0.y*f0.y + f0.z*f0.z + f0.w*f0.w
                 + f1.x*f1.x + f1.y*f1.y + f1.z*f1.z + f1.w*f1.w;
        #pragma unroll
        for (int m = 1; m < 16; m <<= 1) { s += __shfl_xor(s, m); ss += __shfl_xor(ss, m); }
        float mean = s * (1.f / 128.f);
        float var  = ss * (1.f / 128.f) - mean * mean;
        float rstd = rsqrtf(var + 1e-5f);
        float xv[8] = {f0.x, f0.y, f0.z, f0.w, f1.x, f1.y, f1.z, f1.w};
        unsigned short pk[8];
        #pragma unroll
        for (int j = 0; j < 8; j++)
            pk[j] = f2b((xv[j] - mean) * rstd * lnw[c8 + j] + lnb[c8 + j]);
        *(uint4*)(&A_lds[row * 136 + c8]) = *(const uint4*)pk;
    }
    // W tile: fp32 -> bf16
    #pragma unroll
    for (int i = 0; i < 8; i++) {
        int wr = lr + i * 16;
        const float* src = W + (size_t)wr * 128 + c8;
        float4 f0 = *(const float4*)(src);
        float4 f1 = *(const float4*)(src + 4);
        unsigned short pk[8] = {f2b(f0.x), f2b(f0.y), f2b(f0.z), f2b(f0.w),
                                f2b(f1.x), f2b(f1.y), f2b(f1.z), f2b(f1.w)};
        *(uint4*)(&W_lds[wr * 136 + c8]) = *(const uint4*)pk;
    }
    __syncthreads();

    const int w = tid >> 6, lane = tid & 63;
    const int l16 = lane & 15, quad = lane >> 4;
    f32x4 acc[8];
    #pragma unroll
    for (int nt = 0; nt < 8; nt++) acc[nt] = (f32x4){0.f, 0.f, 0.f, 0.f};

    if (gy == 2) {
        // unswapped: C[m][n]; lane rows m = w*16 + quad*4 + rr, col n = nt*16+l16
        #pragma unroll
        for (int k0 = 0; k0 < 128; k0 += 32) {
            short8 a = *(const short8*)(&A_lds[(w * 16 + l16) * 136 + k0 + quad * 8]);
            #pragma unroll
            for (int nt = 0; nt < 8; nt++) {
                short8 b = *(const short8*)(&W_lds[(nt * 16 + l16) * 136 + k0 + quad * 8]);
                acc[nt] = __builtin_amdgcn_mfma_f32_16x16x32_bf16(a, b, acc[nt], 0, 0, 0);
            }
        }
        const int blv = m0 >> 8;                          // strip-local b-row
        const int kl  = (m0 & 255) + w * 16 + quad * 4;   // k position base
        #pragma unroll
        for (int nt = 0; nt < 8; nt++) {
            uint2 pk;
            pk.x = (unsigned)f2b(acc[nt][0]) | ((unsigned)f2b(acc[nt][1]) << 16);
            pk.y = (unsigned)f2b(acc[nt][2]) | ((unsigned)f2b(acc[nt][3]) << 16);
            *(uint2*)(&vt[((size_t)(blv * 128 + nt * 16 + l16)) * 256 + kl]) = pk;
        }
    } else {
        // swapped: C[n][m]; lane cols n = nt*16 + quad*4 + rr, row m = w*16+l16
        #pragma unroll
        for (int k0 = 0; k0 < 128; k0 += 32) {
            short8 a = *(const short8*)(&A_lds[(w * 16 + l16) * 136 + k0 + quad * 8]);
            #pragma unroll
            for (int nt = 0; nt < 8; nt++) {
                short8 b = *(const short8*)(&W_lds[(nt * 16 + l16) * 136 + k0 + quad * 8]);
                acc[nt] = __builtin_amdgcn_mfma_f32_16x16x32_bf16(b, a, acc[nt], 0, 0, 0);
            }
        }
        const int off = (gy == 0) ? 0 : (gy == 1) ? 128 : 256;
        const size_t rowbase = (size_t)(m0 + w * 16 + l16) * SW + off;
        #pragma unroll
        for (int nt = 0; nt < 8; nt++) {
            uint2 pk;
            pk.x = (unsigned)f2b(acc[nt][0]) | ((unsigned)f2b(acc[nt][1]) << 16);
            pk.y = (unsigned)f2b(acc[nt][2]) | ((unsigned)f2b(acc[nt][3]) << 16);
            *(uint2*)(&strip[rowbase + nt * 16 + quad * 4]) = pk;
        }
    }
}

// ---------------------------------------------------------------------------
// K3: attention (MFMA), transposed scores, V^T from global.
// Block = (strip-local b, h); 4 waves x 4 q-tiles.  NO __syncthreads.
// S^T = mfma(K, Q): lane owns row q = q0+l16 -> in-register softmax
// (2 shfl), float4 bias loads, b64 P writes -> PV with vb from Vt (L2)
// -> gated bf16 out.
// ---------------------------------------------------------------------------
__global__ __launch_bounds__(256) void attn_kernel(
    const unsigned short* __restrict__ strip, const unsigned short* __restrict__ vt,
    const float* __restrict__ bm, int b0, unsigned short* __restrict__ gated)
{
    __shared__ __align__(16) unsigned short P_lds[4 * 16 * 264];    // per-wave P
    const int bl = blockIdx.x, h = blockIdx.y;
    const int b  = b0 + bl;
    const int tid = threadIdx.x;
    const int w = tid >> 6, lane = tid & 63;
    const int l16 = lane & 15, quad = lane >> 4;
    const float* bmh = bm + (long)h * NPOS;
    const unsigned short* vth = vt + ((size_t)bl * 128 + h * 32) * 256;
    unsigned short* P_w = P_lds + w * 16 * 264;
    const float scale = 0.17677669529663687f;   // 1/sqrt(32)

    #pragma unroll 1
    for (int i = 0; i < 4; i++) {
        const int q0 = (w * 4 + i) * 16;
        // Q fragment (B operand): row j = l16 -> Q row q0+l16
        short8 bq = *(const short8*)(strip + (size_t)(bl * 256 + q0 + l16) * SW + h * 32 + quad * 8);
        const float* brow = bmh + (size_t)(q0 + l16) * 256 + quad * 4;

        // scores TRANSPOSED: C[k][q]; lane holds q = q0+l16 (col),
        // k = nt*16 + quad*4 + rr (row) -> 4 consecutive k per MFMA.
        float sc[16][4];
        #pragma unroll
        for (int nt = 0; nt < 16; nt++) {
            short8 ka = *(const short8*)(strip + (size_t)(bl * 256 + nt * 16 + l16) * SW + 128 + h * 32 + quad * 8);
            f32x4 c = (f32x4){0.f, 0.f, 0.f, 0.f};
            c = __builtin_amdgcn_mfma_f32_16x16x32_bf16(ka, bq, c, 0, 0, 0);
            float4 bb = *(const float4*)(brow + nt * 16);   // bias[q][k..k+4]
            sc[nt][0] = c[0] * scale + bb.x;
            sc[nt][1] = c[1] * scale + bb.y;
            sc[nt][2] = c[2] * scale + bb.z;
            sc[nt][3] = c[3] * scale + bb.w;
        }

        // row max: 4 independent in-lane chains, then cross-quad (xor 16, 32)
        float m0 = sc[0][0], m1 = sc[0][1], m2 = sc[0][2], m3 = sc[0][3];
        #pragma unroll
        for (int nt = 1; nt < 16; nt++) {
            m0 = fmaxf(m0, sc[nt][0]); m1 = fmaxf(m1, sc[nt][1]);
            m2 = fmaxf(m2, sc[nt][2]); m3 = fmaxf(m3, sc[nt][3]);
        }
        float m = fmaxf(fmaxf(m0, m1), fmaxf(m2, m3));
        m = fmaxf(m, __shfl_xor(m, 16));
        m = fmaxf(m, __shfl_xor(m, 32));

        float s0 = 0.f, s1 = 0.f, s2 = 0.f, s3 = 0.f;
        #pragma unroll
        for (int nt = 0; nt < 16; nt++) {
            float p0_ = __expf(sc[nt][0] - m); sc[nt][0] = p0_; s0 += p0_;
            float p1_ = __expf(sc[nt][1] - m); sc[nt][1] = p1_; s1 += p1_;
            float p2_ = __expf(sc[nt][2] - m); sc[nt][2] = p2_; s2 += p2_;
            float p3_ = __expf(sc[nt][3] - m); sc[nt][3] = p3_; s3 += p3_;
        }
        float ssum = (s0 + s1) + (s2 + s3);
        ssum += __shfl_xor(ssum, 16);
        ssum += __shfl_xor(ssum, 32);
        float inv = 1.f / ssum;            // for row q = q0 + l16

        // P write: row q_local = l16, 4 consecutive k -> one b64 per nt
        #pragma unroll
        for (int nt = 0; nt < 16; nt++) {
            uint2 pk;
            pk.x = (unsigned)f2b(sc[nt][0]) | ((unsigned)f2b(sc[nt][1]) << 16);
            pk.y = (unsigned)f2b(sc[nt][2]) | ((unsigned)f2b(sc[nt][3]) << 16);
            *(uint2*)(&P_w[l16 * 264 + nt * 16 + quad * 4]) = pk;
        }

        f32x4 oacc[2];
        oacc[0] = (f32x4){0.f, 0.f, 0.f, 0.f};
        oacc[1] = (f32x4){0.f, 0.f, 0.f, 0.f};
        #pragma unroll
        for (int kt = 0; kt < 8; kt++) {
            short8 pa = *(const short8*)(&P_w[l16 * 264 + kt * 32 + quad * 8]);
            #pragma unroll
            for (int nh = 0; nh < 2; nh++) {
                short8 vb = *(const short8*)(vth + (size_t)(nh * 16 + l16) * 256 + kt * 32 + quad * 8);
                oacc[nh] = __builtin_amdgcn_mfma_f32_16x16x32_bf16(pa, vb, oacc[nh], 0, 0, 0);
            }
        }
        #pragma unroll
        for (int rr = 0; rr < 4; rr++) {
            float invr = __shfl(inv, quad * 4 + rr);   // denom for row quad*4+rr
            int row = q0 + quad * 4 + rr;
            #pragma unroll
            for (int nh = 0; nh < 2; nh++) {
                int cl = nh * 16 + l16;   // 0..31
                float g = b2f(strip[(size_t)(bl * 256 + row) * SW + 256 + h * 32 + cl]);
                float ov = oacc[nh][rr] * invr;
                ov = ov / (1.f + __expf(-g));
                gated[((size_t)b * 256 + row) * 128 + h * 32 + cl] = f2b(ov);   // bf16
            }
        }
    }
}

// ---------------------------------------------------------------------------
// K4: output projection (MFMA).  gated bf16 -> out fp32.
// Swapped operands (A=Wo, B=gated): lane holds 4 consecutive output cols
// for its row -> float4 C stores.  A-stage is a pure bf16 copy.
// ---------------------------------------------------------------------------
__global__ __launch_bounds__(256) void outproj_mfma_kernel(
    const unsigned short* __restrict__ gated, const float* __restrict__ Wo,
    float* __restrict__ out)
{
    __shared__ __align__(16) unsigned short A_lds[64 * 136];
    __shared__ __align__(16) unsigned short W_lds[128 * 136];
    const int tid = threadIdx.x;
    const int m0 = blockIdx.x * 64;

    const int lr = tid >> 4, c8 = (tid & 15) * 8;
    #pragma unroll
    for (int i = 0; i < 4; i++) {
        int row = lr + i * 16;
        *(uint4*)(&A_lds[row * 136 + c8]) =
            *(const uint4*)(gated + (size_t)(m0 + row) * 128 + c8);
    }
    #pragma unroll
    for (int i = 0; i < 8; i++) {
        const float* src = Wo + (size_t)(lr + i * 16) * 128 + c8;
        float4 f0 = *(const float4*)(src);
        float4 f1 = *(const float4*)(src + 4);
        unsigned short pk[8] = {f2b(f0.x), f2b(f0.y), f2b(f0.z), f2b(f0.w),
                                f2b(f1.x), f2b(f1.y), f2b(f1.z), f2b(f1.w)};
        *(uint4*)(&W_lds[(lr + i * 16) * 136 + c8]) = *(const uint4*)pk;
    }
    __syncthreads();

    const int w = tid >> 6, lane = tid & 63;
    const int l16 = lane & 15, quad = lane >> 4;
    f32x4 acc[8];
    #pragma unroll
    for (int nt = 0; nt < 8; nt++) acc[nt] = (f32x4){0.f, 0.f, 0.f, 0.f};

    #pragma unroll
    for (int k0 = 0; k0 < 128; k0 += 32) {
        short8 a = *(const short8*)(&A_lds[(w * 16 + l16) * 136 + k0 + quad * 8]);
        #pragma unroll
        for (int nt = 0; nt < 8; nt++) {
            short8 b = *(const short8*)(&W_lds[(nt * 16 + l16) * 136 + k0 + quad * 8]);
            // swapped: C[n][m], lane row m = w*16+l16, cols n = nt*16+quad*4+rr
            acc[nt] = __builtin_amdgcn_mfma_f32_16x16x32_bf16(b, a, acc[nt], 0, 0, 0);
        }
    }

    float* orow = out + (size_t)(m0 + w * 16 + l16) * 128;
    #pragma unroll
    for (int nt = 0; nt < 8; nt++)
        *(f32x4*)(&orow[nt * 16 + quad * 4]) = acc[nt];   // fp32 float4
}

// ---------------------------------------------------------------------------
extern "C" void kernel_launch(void* const* d_in, const int* in_sizes, int n_in,
                              void* d_out, int out_size, void* d_ws, size_t ws_size,
                              hipStream_t stream)
{
    (void)in_sizes; (void)n_in; (void)out_size;
    const float* x    = (const float*)d_in[0];
    const float* mask = (const float*)d_in[1];
    const float* lnw  = (const float*)d_in[2];
    const float* lnb  = (const float*)d_in[3];
    const float* Wb   = (const float*)d_in[4];
    const float* Wq   = (const float*)d_in[5];
    const float* Wk   = (const float*)d_in[6];
    const float* Wv   = (const float*)d_in[7];
    const float* Wg   = (const float*)d_in[8];
    const float* Wo   = (const float*)d_in[9];
    float* out = (float*)d_out;   // fp32

    // ws: [bm 1 MB][gated bf16 16 MB][vt HB*64KB][strip HB*192KB]
    const size_t bmB   = (size_t)H_DIM * NPOS * sizeof(float);          // 1 MB
    const size_t gB    = (size_t)NPOS * 128 * sizeof(unsigned short);   // 16 MB
    const size_t perRow = (size_t)256 * SW * 2 + (size_t)128 * 256 * 2; // strip+vt per b-row
    int HB = 256;
    while (HB > 16 && bmB + gB + (size_t)HB * perRow > ws_size) HB >>= 1;

    char* ws = (char*)d_ws;
    float*          bm    = (float*)ws;
    unsigned short* gated = (unsigned short*)(ws + bmB);
    unsigned short* vt    = (unsigned short*)(ws + bmB + gB);
    unsigned short* strip = vt + (size_t)HB * 128 * 256;

    ln_biasmask_kernel<<<NPOS / 4, 256, 0, stream>>>(x, mask, lnw, lnb, Wb, bm);
    for (int b0 = 0; b0 < S_DIM; b0 += HB) {
        proj_ln_kernel<<<dim3(HB * 4, 4), 256, 0, stream>>>(
            x, lnw, lnb, Wq, Wk, Wv, Wg, b0 * 256, strip, vt);
        attn_kernel<<<dim3(HB, H_DIM), 256, 0, stream>>>(strip, vt, bm, b0, gated);
    }
    outproj_mfma_kernel<<<NPOS / 64, 256, 0, stream>>>(gated, Wo, out);
}